// Round 1
// baseline (1036.960 us; speedup 1.0000x reference)
//
#include <hip/hip_runtime.h>

#define DEV __device__ __forceinline__

typedef __attribute__((ext_vector_type(4))) float f32x4;
typedef __attribute__((ext_vector_type(8))) __bf16 bf16x8;

static constexpr int Bc = 256;      // batch
static constexpr int Sc = 200;      // seq
static constexpr int Hc = 64;       // hidden
static constexpr int Ec = 768;      // emb
static constexpr int HDc = 32;      // head dim
static constexpr int NROWS = Bc * Sc;   // 51200

// ---------- helpers ----------
DEV __bf16 f2bf(float f) {
    unsigned u = __builtin_bit_cast(unsigned, f);
    unsigned r = (u + 0x7fffu + ((u >> 16) & 1u)) >> 16;   // RNE
    unsigned short s = (unsigned short)r;
    return __builtin_bit_cast(__bf16, s);
}

// 8 consecutive fp32 -> bf16x8 A/B fragment (16B-aligned source)
DEV bf16x8 load_frag8(const float* __restrict__ p) {
    f32x4 a = *(const f32x4*)p;
    f32x4 b = *(const f32x4*)(p + 4);
    bf16x8 r;
    r[0] = f2bf(a[0]); r[1] = f2bf(a[1]); r[2] = f2bf(a[2]); r[3] = f2bf(a[3]);
    r[4] = f2bf(b[0]); r[5] = f2bf(b[1]); r[6] = f2bf(b[2]); r[7] = f2bf(b[3]);
    return r;
}

// B fragment from row-major W[K][64]: lane holds B[k][n], k = k0+j
DEV bf16x8 load_wfrag(const float* __restrict__ W, int k0, int n) {
    bf16x8 r;
#pragma unroll
    for (int j = 0; j < 8; j++) r[j] = f2bf(W[(k0 + j) * Hc + n]);
    return r;
}

// ---------- feat = LN((rev[t]+meta[t]) @ featW + featb) ----------
// block = 4 waves; each wave: 16-row m-tile, MFMA over K=768, fused row-LN epilogue
__global__ __launch_bounds__(256) void feat_kernel(
    const int* __restrict__ tseq, const float* __restrict__ rev,
    const float* __restrict__ meta, const float* __restrict__ featW,
    const float* __restrict__ featb, const float* __restrict__ g,
    const float* __restrict__ bb, float* __restrict__ out)
{
    int lane = threadIdx.x & 63, wv = threadIdx.x >> 6;
    int ln = lane & 15, quad = lane >> 4;
    int m0 = blockIdx.x * 64 + wv * 16;          // NROWS % 64 == 0
    long t = tseq[m0 + ln];
    const float* rp = rev + t * Ec + quad * 8;
    const float* mp = meta + t * Ec + quad * 8;

    f32x4 acc[4];
#pragma unroll
    for (int nt = 0; nt < 4; nt++) acc[nt] = (f32x4){0.f, 0.f, 0.f, 0.f};

    for (int ks = 0; ks < Ec / 32; ks++) {
        f32x4 ra = *(const f32x4*)(rp + ks * 32);
        f32x4 rb = *(const f32x4*)(rp + ks * 32 + 4);
        f32x4 ma = *(const f32x4*)(mp + ks * 32);
        f32x4 mb = *(const f32x4*)(mp + ks * 32 + 4);
        bf16x8 a;
        a[0] = f2bf(ra[0] + ma[0]); a[1] = f2bf(ra[1] + ma[1]);
        a[2] = f2bf(ra[2] + ma[2]); a[3] = f2bf(ra[3] + ma[3]);
        a[4] = f2bf(rb[0] + mb[0]); a[5] = f2bf(rb[1] + mb[1]);
        a[6] = f2bf(rb[2] + mb[2]); a[7] = f2bf(rb[3] + mb[3]);
#pragma unroll
        for (int nt = 0; nt < 4; nt++) {
            bf16x8 bf = load_wfrag(featW, ks * 32 + quad * 8, nt * 16 + ln);
            acc[nt] = __builtin_amdgcn_mfma_f32_16x16x32_bf16(a, bf, acc[nt], 0, 0, 0);
        }
    }
    // fused LayerNorm (eps=1e-5): each quad-group of 16 lanes holds one row per reg
#pragma unroll
    for (int reg = 0; reg < 4; reg++) {
        float vals[4]; float s = 0.f, s2 = 0.f;
#pragma unroll
        for (int nt = 0; nt < 4; nt++) {
            float v = acc[nt][reg] + featb[nt * 16 + ln];
            vals[nt] = v; s += v; s2 += v * v;
        }
#pragma unroll
        for (int m = 1; m <= 8; m <<= 1) { s += __shfl_xor(s, m, 64); s2 += __shfl_xor(s2, m, 64); }
        float mean = s * (1.f / 64.f);
        float var = s2 * (1.f / 64.f) - mean * mean;
        float inv = rsqrtf(var + 1e-5f);
        int r = m0 + quad * 4 + reg;
#pragma unroll
        for (int nt = 0; nt < 4; nt++) {
            int c = nt * 16 + ln;
            out[r * Hc + c] = (vals[nt] - mean) * inv * g[c] + bb[c];
        }
    }
}

// ---------- q = item_emb[t] * (t != 0) ----------
__global__ __launch_bounds__(256) void qinit_kernel(
    const int* __restrict__ tseq, const float* __restrict__ item, float* __restrict__ q)
{
    int gid = blockIdx.x * 256 + threadIdx.x;    // one float4 each
    int r = gid >> 4, c4 = (gid & 15) * 4;
    long t = tseq[r];
    f32x4 v = *(const f32x4*)(item + t * Hc + c4);
    float k = (t != 0) ? 1.f : 0.f;
    v *= k;
    *(f32x4*)(q + (long)r * Hc + c4) = v;
}

// ---------- generic Y = [relu](X @ W + b) [+res] [*keep], optional second W set ----------
__global__ __launch_bounds__(256) void proj_kernel(
    const float* __restrict__ X, int Nrows,
    const float* __restrict__ W0, const float* __restrict__ b0, float* __restrict__ Y0,
    const float* __restrict__ W1, const float* __restrict__ b1, float* __restrict__ Y1,
    const float* __restrict__ res, const int* __restrict__ keep, int doRelu)
{
    int lane = threadIdx.x & 63, wv = threadIdx.x >> 6;
    int ln = lane & 15, quad = lane >> 4;
    int m0 = blockIdx.x * 64 + wv * 16;
    int arow = m0 + ln; if (arow > Nrows - 1) arow = Nrows - 1;
    bf16x8 a0 = load_frag8(X + (long)arow * Hc + quad * 8);
    bf16x8 a1 = load_frag8(X + (long)arow * Hc + 32 + quad * 8);

    int nsets = (W1 != nullptr) ? 2 : 1;
    for (int si = 0; si < nsets; si++) {
        const float* W = si ? W1 : W0;
        const float* bias = si ? b1 : b0;
        float* Y = si ? Y1 : Y0;
#pragma unroll
        for (int nt = 0; nt < 4; nt++) {
            int col = nt * 16 + ln;
            bf16x8 w0 = load_wfrag(W, quad * 8, col);
            bf16x8 w1 = load_wfrag(W, 32 + quad * 8, col);
            f32x4 acc = (f32x4){0.f, 0.f, 0.f, 0.f};
            acc = __builtin_amdgcn_mfma_f32_16x16x32_bf16(a0, w0, acc, 0, 0, 0);
            acc = __builtin_amdgcn_mfma_f32_16x16x32_bf16(a1, w1, acc, 0, 0, 0);
            float bv = bias[col];
#pragma unroll
            for (int reg = 0; reg < 4; reg++) {
                int r = m0 + quad * 4 + reg;
                if (r < Nrows) {
                    float v = acc[reg] + bv;
                    if (doRelu) v = fmaxf(v, 0.f);
                    if (res) v += res[(long)r * Hc + col];
                    if (keep) v *= (keep[r] != 0) ? 1.f : 0.f;
                    Y[(long)r * Hc + col] = v;
                }
            }
        }
    }
}

// ---------- wave-per-row LayerNorm ----------
__global__ __launch_bounds__(256) void ln_rows(
    const float* __restrict__ X, const float* __restrict__ g,
    const float* __restrict__ b, float* __restrict__ Y, float eps)
{
    int row = blockIdx.x * 4 + (threadIdx.x >> 6);
    int lane = threadIdx.x & 63;
    float v = X[(long)row * Hc + lane];
    float s = v, s2 = v * v;
#pragma unroll
    for (int m = 1; m <= 32; m <<= 1) { s += __shfl_xor(s, m, 64); s2 += __shfl_xor(s2, m, 64); }
    float mean = s * (1.f / 64.f);
    float var = s2 * (1.f / 64.f) - mean * mean;
    Y[(long)row * Hc + lane] = (v - mean) * rsqrtf(var + eps) * g[lane] + b[lane];
}

// ---------- attention per (b, head): S = (Q96 K96^T)*scale, causal softmax, ctx = P V ----------
// Q96/K96 = concat(item, position, feature) 96-dim q/k-side vectors.
__global__ __launch_bounds__(256) void attn_kernel(
    const float* __restrict__ qp, const float* __restrict__ kp, const float* __restrict__ vp,
    const float* __restrict__ pqp, const float* __restrict__ pkp,
    const float* __restrict__ fqp, const float* __restrict__ fkp,
    float* __restrict__ ctx)
{
    __shared__ float Sm[16 * 208];        // score tile; P (bf16) overlays same rows
    __shared__ __bf16 Vt[32 * 224];       // V transposed [vdim][key], key-padded

    int bb = blockIdx.x >> 1, h = blockIdx.x & 1;
    int tid = threadIdx.x;
    int lane = tid & 63, wv = tid >> 6;
    int ln = lane & 15, quad = lane >> 4;
    const int hc = h * HDc;
    const long base = (long)bb * Sc;
    const float scale = 0.17677669529663687f;   // 1/sqrt(32)
    __bf16* P = (__bf16*)Sm;                    // row stride 416 bf16 (= 832 B)

    // stage V^T in bf16 (zero the key-pad so pad never produces NaN via MFMA)
    for (int idx = tid; idx < Sc * HDc; idx += 256) {
        int k = idx >> 5, n = idx & 31;
        Vt[n * 224 + k] = f2bf(vp[(base + k) * Hc + hc + n]);
    }
    for (int idx = tid; idx < HDc * 24; idx += 256) {
        int n = idx / 24, k = 200 + idx % 24;
        Vt[n * 224 + k] = __builtin_bit_cast(__bf16, (unsigned short)0);
    }

    for (int t = 0; t < 13; t++) {               // 13 q-tiles of 16 rows
        __syncthreads();                          // also covers Vt staging at t=0
        // ---- q-side fragments for this tile (all waves identical)
        int arow = t * 16 + ln; if (arow > Sc - 1) arow = Sc - 1;
        bf16x8 aq0 = load_frag8(qp + (base + arow) * Hc + hc + quad * 8);
        bf16x8 aq1 = load_frag8(pqp + (long)arow * Hc + hc + quad * 8);
        bf16x8 aq2 = load_frag8(fqp + (base + arow) * Hc + hc + quad * 8);
        // ---- scores: key-tiles split over waves
        for (int nt = wv; nt <= t; nt += 4) {
            int key = nt * 16 + ln; if (key > Sc - 1) key = Sc - 1;
            f32x4 acc = (f32x4){0.f, 0.f, 0.f, 0.f};
            bf16x8 b0 = load_frag8(kp + (base + key) * Hc + hc + quad * 8);
            acc = __builtin_amdgcn_mfma_f32_16x16x32_bf16(aq0, b0, acc, 0, 0, 0);
            bf16x8 b1 = load_frag8(pkp + (long)key * Hc + hc + quad * 8);
            acc = __builtin_amdgcn_mfma_f32_16x16x32_bf16(aq1, b1, acc, 0, 0, 0);
            bf16x8 b2 = load_frag8(fkp + (base + key) * Hc + hc + quad * 8);
            acc = __builtin_amdgcn_mfma_f32_16x16x32_bf16(aq2, b2, acc, 0, 0, 0);
#pragma unroll
            for (int reg = 0; reg < 4; reg++)
                Sm[(quad * 4 + reg) * 208 + nt * 16 + ln] = acc[reg] * scale;
        }
        __syncthreads();
        // ---- causal softmax, rows 4*wv..4*wv+3 (reads S row then overwrites with bf16 P)
        for (int ri = 0; ri < 4; ri++) {
            int r = wv * 4 + ri;
            int qrow = t * 16 + r;               // >= Sc only for phantom rows (never written out)
            float sv[4]; float mx = -1e30f;
#pragma unroll
            for (int j = 0; j < 4; j++) {
                int k = lane + 64 * j;
                sv[j] = (k <= qrow && k < 208) ? Sm[r * 208 + k] : -1e30f;
                mx = fmaxf(mx, sv[j]);
            }
#pragma unroll
            for (int m = 1; m <= 32; m <<= 1) mx = fmaxf(mx, __shfl_xor(mx, m, 64));
            float sum = 0.f; float pv[4];
#pragma unroll
            for (int j = 0; j < 4; j++) {
                float e = (sv[j] > -1e29f) ? __expf(sv[j] - mx) : 0.f;
                pv[j] = e; sum += e;
            }
#pragma unroll
            for (int m = 1; m <= 32; m <<= 1) sum += __shfl_xor(sum, m, 64);
            float inv = 1.f / sum;
#pragma unroll
            for (int j = 0; j < 4; j++) {
                int k = lane + 64 * j;
                if (k < 224) P[r * 416 + k] = f2bf(pv[j] * inv);   // zero beyond qrow
            }
        }
        __syncthreads();
        // ---- ctx tile = P @ V  (waves 0,1 take the two 16-wide vdim tiles)
        if (wv < 2) {
            int ksteps = (t + 2) >> 1;           // ceil(16(t+1)/32), =7 at t=12
            f32x4 acc = (f32x4){0.f, 0.f, 0.f, 0.f};
            const char* Pb = (const char*)Sm;
            for (int ks = 0; ks < ksteps; ks++) {
                bf16x8 pa = *(const bf16x8*)(Pb + ln * 832 + ks * 64 + quad * 16);
                bf16x8 vb = *(const bf16x8*)(&Vt[(wv * 16 + ln) * 224 + ks * 32 + quad * 8]);
                acc = __builtin_amdgcn_mfma_f32_16x16x32_bf16(pa, vb, acc, 0, 0, 0);
            }
#pragma unroll
            for (int reg = 0; reg < 4; reg++) {
                int r = t * 16 + quad * 4 + reg;
                if (r < Sc) ctx[(base + r) * Hc + hc + wv * 16 + ln] = acc[reg];
            }
        }
    }
}

// ---------- logits ----------
__global__ __launch_bounds__(256) void logits_kernel(
    const float* __restrict__ lf, const int* __restrict__ pos, const int* __restrict__ neg,
    const float* __restrict__ item, float* __restrict__ out)
{
    int row = blockIdx.x * 4 + (threadIdx.x >> 6);
    int lane = threadIdx.x & 63;
    float v = lf[(long)row * Hc + lane];
    long p = pos[row], n = neg[row];
    float dp = v * item[p * Hc + lane];
    float dn = v * item[n * Hc + lane];
#pragma unroll
    for (int m = 1; m <= 32; m <<= 1) { dp += __shfl_xor(dp, m, 64); dn += __shfl_xor(dn, m, 64); }
    if (lane == 0) { out[row] = dp; out[NROWS + row] = dn; }
}

// ---------- launch ----------
extern "C" void kernel_launch(void* const* d_in, const int* in_sizes, int n_in,
                              void* d_out, int out_size, void* d_ws, size_t ws_size,
                              hipStream_t stream)
{
    const int* tseq = (const int*)d_in[0];
    const int* pos  = (const int*)d_in[1];
    const int* neg  = (const int*)d_in[2];
    const float* rev   = (const float*)d_in[3];
    const float* meta  = (const float*)d_in[4];
    const float* item  = (const float*)d_in[5];
    const float* pe    = (const float*)d_in[6];
    const float* featW = (const float*)d_in[7];
    const float* featb = (const float*)d_in[8];
    const float* rg    = (const float*)d_in[9];
    const float* rb    = (const float*)d_in[10];
    const float* Wq = (const float*)d_in[11]; const float* Wk = (const float*)d_in[12];
    const float* Wv = (const float*)d_in[13]; const float* Wpq = (const float*)d_in[14];
    const float* Wpk = (const float*)d_in[15]; const float* Wfq = (const float*)d_in[16];
    const float* Wfk = (const float*)d_in[17]; const float* Wo = (const float*)d_in[18];
    const float* W1 = (const float*)d_in[19]; const float* W2 = (const float*)d_in[20];
    const float* bq = (const float*)d_in[21]; const float* bk = (const float*)d_in[22];
    const float* bv = (const float*)d_in[23]; const float* bpq = (const float*)d_in[24];
    const float* bpk = (const float*)d_in[25]; const float* bfq = (const float*)d_in[26];
    const float* bfk = (const float*)d_in[27]; const float* bo = (const float*)d_in[28];
    const float* b1 = (const float*)d_in[29]; const float* b2 = (const float*)d_in[30];
    const float* ag = (const float*)d_in[31]; const float* ab = (const float*)d_in[32];
    const float* fg = (const float*)d_in[33]; const float* fb = (const float*)d_in[34];
    const float* lg = (const float*)d_in[35]; const float* lb = (const float*)d_in[36];
    float* out = (float*)d_out;

    float* ws = (float*)d_ws;
    const size_t F = (size_t)NROWS * Hc;
    float* feat = ws;
    float* q    = ws + 1 * F;
    float* Qn   = ws + 2 * F;
    float* qp   = ws + 3 * F;   // also ctx (row/phase-disjoint)
    float* kp   = ws + 4 * F;   // also FFN hidden
    float* vp   = ws + 5 * F;
    float* fqp  = ws + 6 * F;
    float* fkp  = ws + 7 * F;
    float* pqp  = ws + 8 * F;
    float* pkp  = pqp + (size_t)Sc * Hc;

    const int PB = NROWS / 64;     // 800 proj blocks
    const int LB = NROWS / 4;      // 12800 LN blocks

    feat_kernel<<<PB, 256, 0, stream>>>(tseq, rev, meta, featW, featb, rg, rb, feat);
    qinit_kernel<<<NROWS * Hc / 4 / 256, 256, 0, stream>>>(tseq, item, q);

    for (int i = 0; i < 2; i++) {
        const float* Wq_i = Wq + i * Hc * Hc;  const float* bq_i = bq + i * Hc;
        const float* Wk_i = Wk + i * Hc * Hc;  const float* bk_i = bk + i * Hc;
        const float* Wv_i = Wv + i * Hc * Hc;  const float* bv_i = bv + i * Hc;
        const float* Wpq_i = Wpq + i * Hc * Hc; const float* bpq_i = bpq + i * Hc;
        const float* Wpk_i = Wpk + i * Hc * Hc; const float* bpk_i = bpk + i * Hc;
        const float* Wfq_i = Wfq + i * Hc * Hc; const float* bfq_i = bfq + i * Hc;
        const float* Wfk_i = Wfk + i * Hc * Hc; const float* bfk_i = bfk + i * Hc;
        const float* Wo_i = Wo + i * Hc * Hc;  const float* bo_i = bo + i * Hc;
        const float* W1_i = W1 + i * Hc * Hc;  const float* b1_i = b1 + i * Hc;
        const float* W2_i = W2 + i * Hc * Hc;  const float* b2_i = b2 + i * Hc;

        ln_rows<<<LB, 256, 0, stream>>>(q, ag + i * Hc, ab + i * Hc, Qn, 1e-8f);
        proj_kernel<<<PB, 256, 0, stream>>>(Qn, NROWS, Wq_i, bq_i, qp,
                                            nullptr, nullptr, nullptr, nullptr, nullptr, 0);
        proj_kernel<<<PB, 256, 0, stream>>>(q, NROWS, Wk_i, bk_i, kp,
                                            Wv_i, bv_i, vp, nullptr, nullptr, 0);
        proj_kernel<<<PB, 256, 0, stream>>>(feat, NROWS, Wfq_i, bfq_i, fqp,
                                            Wfk_i, bfk_i, fkp, nullptr, nullptr, 0);
        proj_kernel<<<(Sc + 63) / 64, 256, 0, stream>>>(pe, Sc, Wpq_i, bpq_i, pqp,
                                            Wpk_i, bpk_i, pkp, nullptr, nullptr, 0);
        attn_kernel<<<Bc * 2, 256, 0, stream>>>(qp, kp, vp, pqp, pkp, fqp, fkp, /*ctx=*/qp);
        proj_kernel<<<PB, 256, 0, stream>>>(qp, NROWS, Wo_i, bo_i, q,
                                            nullptr, nullptr, nullptr, /*res=*/Qn, nullptr, 0);
        ln_rows<<<LB, 256, 0, stream>>>(q, fg + i * Hc, fb + i * Hc, q, 1e-8f);
        proj_kernel<<<PB, 256, 0, stream>>>(q, NROWS, W1_i, b1_i, kp,
                                            nullptr, nullptr, nullptr, nullptr, nullptr, 1);
        proj_kernel<<<PB, 256, 0, stream>>>(kp, NROWS, W2_i, b2_i, q,
                                            nullptr, nullptr, nullptr, /*res=*/q, tseq, 0);
    }
    ln_rows<<<LB, 256, 0, stream>>>(q, lg, lb, q, 1e-8f);
    logits_kernel<<<LB, 256, 0, stream>>>(q, pos, neg, item, out);
}

// Round 2
// 883.178 us; speedup vs baseline: 1.1741x; 1.1741x over previous
//
#include <hip/hip_runtime.h>

#define DEV __device__ __forceinline__

typedef __attribute__((ext_vector_type(4))) float f32x4;
typedef __attribute__((ext_vector_type(8))) __bf16 bf16x8;

static constexpr int Bc = 256;      // batch
static constexpr int Sc = 200;      // seq
static constexpr int Hc = 64;       // hidden
static constexpr int Ec = 768;      // emb
static constexpr int HDc = 32;      // head dim
static constexpr int NROWS = Bc * Sc;   // 51200

// ---------- helpers ----------
DEV __bf16 f2bf(float f) {
    unsigned u = __builtin_bit_cast(unsigned, f);
    unsigned short s = (unsigned short)((u + 0x7fffu + ((u >> 16) & 1u)) >> 16);  // RNE
    return __builtin_bit_cast(__bf16, s);
}
DEV float bf2f(__bf16 h) {
    unsigned short s = __builtin_bit_cast(unsigned short, h);
    unsigned u = ((unsigned)s) << 16;
    return __builtin_bit_cast(float, u);
}
DEV bf16x8 ld8(const __bf16* p) { return *(const bf16x8*)p; }

// 8 consecutive fp32 -> bf16x8 fragment
DEV bf16x8 cvt8(const float* __restrict__ p) {
    f32x4 a = *(const f32x4*)p;
    f32x4 b = *(const f32x4*)(p + 4);
    bf16x8 r;
    r[0] = f2bf(a[0]); r[1] = f2bf(a[1]); r[2] = f2bf(a[2]); r[3] = f2bf(a[3]);
    r[4] = f2bf(b[0]); r[5] = f2bf(b[1]); r[6] = f2bf(b[2]); r[7] = f2bf(b[3]);
    return r;
}

// 64x64 GEMM tile: Y[m0..m0+15][:] = A(16x64) @ W^T-layout(bf16 [n][k]) + bias
DEV void gemm64(bf16x8 A0, bf16x8 A1, const __bf16* __restrict__ W,
                const float* __restrict__ bias, __bf16* __restrict__ Y,
                int m0, int ln, int quad, int maxrow)
{
#pragma unroll
    for (int nt = 0; nt < 4; nt++) {
        int col = nt * 16 + ln;
        bf16x8 w0 = ld8(W + col * 64 + quad * 8);
        bf16x8 w1 = ld8(W + col * 64 + 32 + quad * 8);
        f32x4 acc = (f32x4){0.f, 0.f, 0.f, 0.f};
        acc = __builtin_amdgcn_mfma_f32_16x16x32_bf16(A0, w0, acc, 0, 0, 0);
        acc = __builtin_amdgcn_mfma_f32_16x16x32_bf16(A1, w1, acc, 0, 0, 0);
        float bv = bias[col];
#pragma unroll
        for (int reg = 0; reg < 4; reg++) {
            int r = m0 + quad * 4 + reg;
            if (r < maxrow) Y[(long)r * 64 + col] = f2bf(acc[reg] + bv);
        }
    }
}

// ---------- one-shot weight transpose + bf16 convert ----------
// featW [768][64] -> featWt [64][768];  10 x [2][64][64] -> Wt[mat][l][n][k]
__global__ __launch_bounds__(256) void wconv_kernel(
    const float* __restrict__ featW,
    const float* __restrict__ Wq, const float* __restrict__ Wk, const float* __restrict__ Wv,
    const float* __restrict__ Wpq, const float* __restrict__ Wpk,
    const float* __restrict__ Wfq, const float* __restrict__ Wfk,
    const float* __restrict__ Wo, const float* __restrict__ W1, const float* __restrict__ W2,
    __bf16* __restrict__ featWt, __bf16* __restrict__ Wt)
{
    int gid = blockIdx.x * 256 + threadIdx.x;
    if (gid < Ec * Hc) {
        int k = gid >> 6, n = gid & 63;
        featWt[n * Ec + k] = f2bf(featW[gid]);
        return;
    }
    int e2 = gid - Ec * Hc;                 // 0 .. 81919
    int mat = e2 >> 13, r = e2 & 8191, l = r >> 12, e = r & 4095, k = e >> 6, n = e & 63;
    const float* Ws[10] = {Wq, Wk, Wv, Wpq, Wpk, Wfq, Wfk, Wo, W1, W2};
    Wt[mat * 8192 + l * 4096 + n * 64 + k] = f2bf(Ws[mat][l * 4096 + e]);
}

// ---------- feat = LN((rev[t]+meta[t]) @ featW + featb), bf16 out ----------
__global__ __launch_bounds__(256) void feat_kernel(
    const int* __restrict__ tseq, const float* __restrict__ rev,
    const float* __restrict__ meta, const __bf16* __restrict__ featWt,
    const float* __restrict__ featb, const float* __restrict__ g,
    const float* __restrict__ bb, __bf16* __restrict__ out)
{
    int lane = threadIdx.x & 63, wv = threadIdx.x >> 6;
    int ln = lane & 15, quad = lane >> 4;
    int m0 = blockIdx.x * 64 + wv * 16;
    long t = tseq[m0 + ln];
    const float* rp = rev + t * Ec + quad * 8;
    const float* mp = meta + t * Ec + quad * 8;

    f32x4 acc[4];
#pragma unroll
    for (int nt = 0; nt < 4; nt++) acc[nt] = (f32x4){0.f, 0.f, 0.f, 0.f};

    for (int ks = 0; ks < Ec / 32; ks++) {
        f32x4 ra = *(const f32x4*)(rp + ks * 32);
        f32x4 rb = *(const f32x4*)(rp + ks * 32 + 4);
        f32x4 ma = *(const f32x4*)(mp + ks * 32);
        f32x4 mb = *(const f32x4*)(mp + ks * 32 + 4);
        bf16x8 a;
        a[0] = f2bf(ra[0] + ma[0]); a[1] = f2bf(ra[1] + ma[1]);
        a[2] = f2bf(ra[2] + ma[2]); a[3] = f2bf(ra[3] + ma[3]);
        a[4] = f2bf(rb[0] + mb[0]); a[5] = f2bf(rb[1] + mb[1]);
        a[6] = f2bf(rb[2] + mb[2]); a[7] = f2bf(rb[3] + mb[3]);
#pragma unroll
        for (int nt = 0; nt < 4; nt++) {
            bf16x8 bf = ld8(featWt + (nt * 16 + ln) * Ec + ks * 32 + quad * 8);
            acc[nt] = __builtin_amdgcn_mfma_f32_16x16x32_bf16(a, bf, acc[nt], 0, 0, 0);
        }
    }
#pragma unroll
    for (int reg = 0; reg < 4; reg++) {
        float vals[4]; float s = 0.f, s2 = 0.f;
#pragma unroll
        for (int nt = 0; nt < 4; nt++) {
            float v = acc[nt][reg] + featb[nt * 16 + ln];
            vals[nt] = v; s += v; s2 += v * v;
        }
#pragma unroll
        for (int m = 1; m <= 8; m <<= 1) { s += __shfl_xor(s, m, 64); s2 += __shfl_xor(s2, m, 64); }
        float mean = s * (1.f / 64.f);
        float var = s2 * (1.f / 64.f) - mean * mean;
        float inv = rsqrtf(var + 1e-5f);
        int r = m0 + quad * 4 + reg;
#pragma unroll
        for (int nt = 0; nt < 4; nt++) {
            int c = nt * 16 + ln;
            out[(long)r * Hc + c] = f2bf((vals[nt] - mean) * inv * g[c] + bb[c]);
        }
    }
}

// ---------- q = item_emb[t] * (t != 0), bf16 out ----------
__global__ __launch_bounds__(256) void qinit_kernel(
    const int* __restrict__ tseq, const float* __restrict__ item, __bf16* __restrict__ q)
{
    int gid = blockIdx.x * 256 + threadIdx.x;   // 8 elements each
    int r = gid >> 3, c = (gid & 7) * 8;
    long t = tseq[r];
    f32x4 v0 = *(const f32x4*)(item + t * Hc + c);
    f32x4 v1 = *(const f32x4*)(item + t * Hc + c + 4);
    float k = (t != 0) ? 1.f : 0.f;
    bf16x8 o;
    o[0] = f2bf(v0[0] * k); o[1] = f2bf(v0[1] * k); o[2] = f2bf(v0[2] * k); o[3] = f2bf(v0[3] * k);
    o[4] = f2bf(v1[0] * k); o[5] = f2bf(v1[1] * k); o[6] = f2bf(v1[2] * k); o[7] = f2bf(v1[3] * k);
    *(bf16x8*)(q + (long)r * Hc + c) = o;
}

// ---------- pe projections for both layers: pq/pk = pe @ Wp* + b ----------
__global__ __launch_bounds__(256) void pe_kernel(
    const float* __restrict__ pe, const __bf16* __restrict__ Wt,
    const float* __restrict__ bpq, const float* __restrict__ bpk,
    __bf16* __restrict__ pqp, __bf16* __restrict__ pkp)
{
    int l = blockIdx.x >> 2, rb = blockIdx.x & 3;
    int lane = threadIdx.x & 63, wv = threadIdx.x >> 6;
    int ln = lane & 15, quad = lane >> 4;
    int m0 = rb * 64 + wv * 16;
    int arow = m0 + ln; if (arow > Sc - 1) arow = Sc - 1;
    bf16x8 a0 = cvt8(pe + arow * Hc + quad * 8);
    bf16x8 a1 = cvt8(pe + arow * Hc + 32 + quad * 8);
    gemm64(a0, a1, Wt + 3 * 8192 + l * 4096, bpq + l * 64, pqp + l * Sc * Hc, m0, ln, quad, Sc);
    gemm64(a0, a1, Wt + 4 * 8192 + l * 4096, bpk + l * 64, pkp + l * Sc * Hc, m0, ln, quad, Sc);
}

// ---------- fused: Qn = LN(q); 5 projections q/k/v/fq/fk ----------
__global__ __launch_bounds__(256) void qkvf_kernel(
    const __bf16* __restrict__ q, const __bf16* __restrict__ feat,
    const __bf16* __restrict__ Wt, int layer,
    const float* __restrict__ bq, const float* __restrict__ bk, const float* __restrict__ bv,
    const float* __restrict__ bfq, const float* __restrict__ bfk,
    const float* __restrict__ ag, const float* __restrict__ ab,
    __bf16* __restrict__ Qn, __bf16* __restrict__ qp, __bf16* __restrict__ kp,
    __bf16* __restrict__ vp, __bf16* __restrict__ fqp, __bf16* __restrict__ fkp)
{
    int lane = threadIdx.x & 63, wv = threadIdx.x >> 6;
    int ln = lane & 15, quad = lane >> 4;
    int m0 = blockIdx.x * 64 + wv * 16;
    long row = m0 + ln;
    bf16x8 aq0 = ld8(q + row * 64 + quad * 8);
    bf16x8 aq1 = ld8(q + row * 64 + 32 + quad * 8);
    bf16x8 af0 = ld8(feat + row * 64 + quad * 8);
    bf16x8 af1 = ld8(feat + row * 64 + 32 + quad * 8);

    // LN over the row (lane holds 16 of row ln's 64 elems; partners differ in bits 4,5)
    float s = 0.f, s2 = 0.f;
#pragma unroll
    for (int j = 0; j < 8; j++) {
        float v = bf2f(aq0[j]); s += v; s2 += v * v;
        v = bf2f(aq1[j]); s += v; s2 += v * v;
    }
    s += __shfl_xor(s, 16, 64); s += __shfl_xor(s, 32, 64);
    s2 += __shfl_xor(s2, 16, 64); s2 += __shfl_xor(s2, 32, 64);
    float mean = s * (1.f / 64.f);
    float inv = rsqrtf(s2 * (1.f / 64.f) - mean * mean + 1e-8f);
    const float* agl = ag + layer * 64; const float* abl = ab + layer * 64;
    bf16x8 nq0, nq1;
#pragma unroll
    for (int j = 0; j < 8; j++) {
        int k0 = quad * 8 + j, k1 = 32 + quad * 8 + j;
        nq0[j] = f2bf((bf2f(aq0[j]) - mean) * inv * agl[k0] + abl[k0]);
        nq1[j] = f2bf((bf2f(aq1[j]) - mean) * inv * agl[k1] + abl[k1]);
    }
    *(bf16x8*)(Qn + row * 64 + quad * 8) = nq0;
    *(bf16x8*)(Qn + row * 64 + 32 + quad * 8) = nq1;

    gemm64(nq0, nq1, Wt + 0 * 8192 + layer * 4096, bq + layer * 64, qp, m0, ln, quad, NROWS);
    gemm64(aq0, aq1, Wt + 1 * 8192 + layer * 4096, bk + layer * 64, kp, m0, ln, quad, NROWS);
    gemm64(aq0, aq1, Wt + 2 * 8192 + layer * 4096, bv + layer * 64, vp, m0, ln, quad, NROWS);
    gemm64(af0, af1, Wt + 5 * 8192 + layer * 4096, bfq + layer * 64, fqp, m0, ln, quad, NROWS);
    gemm64(af0, af1, Wt + 6 * 8192 + layer * 4096, bfk + layer * 64, fkp, m0, ln, quad, NROWS);
}

// ---------- attention per (b, head) ----------
__global__ __launch_bounds__(256) void attn_kernel(
    const __bf16* __restrict__ qp, const __bf16* __restrict__ kp, const __bf16* __restrict__ vp,
    const __bf16* __restrict__ pqp, const __bf16* __restrict__ pkp,
    const __bf16* __restrict__ fqp, const __bf16* __restrict__ fkp,
    __bf16* __restrict__ ctx)
{
    __shared__ float Sm[16 * 208];        // score tile; P (bf16) overlays same rows
    __shared__ __bf16 Vt[32 * 224];       // V transposed [vdim][key], key-padded

    int bb = blockIdx.x >> 1, h = blockIdx.x & 1;
    int tid = threadIdx.x;
    int lane = tid & 63, wv = tid >> 6;
    int ln = lane & 15, quad = lane >> 4;
    const int hc = h * HDc;
    const long base = (long)bb * Sc;
    const float scale = 0.17677669529663687f;   // 1/sqrt(32)
    __bf16* P = (__bf16*)Sm;                    // row stride 416 bf16 (= 832 B)

    for (int idx = tid; idx < Sc * HDc; idx += 256) {
        int k = idx >> 5, n = idx & 31;
        Vt[n * 224 + k] = vp[(base + k) * Hc + hc + n];
    }
    for (int idx = tid; idx < HDc * 24; idx += 256) {
        int n = idx / 24, k = 200 + idx % 24;
        Vt[n * 224 + k] = __builtin_bit_cast(__bf16, (unsigned short)0);
    }

    for (int t = 0; t < 13; t++) {
        __syncthreads();
        int arow = t * 16 + ln; if (arow > Sc - 1) arow = Sc - 1;
        bf16x8 aq0 = ld8(qp + (base + arow) * Hc + hc + quad * 8);
        bf16x8 aq1 = ld8(pqp + (long)arow * Hc + hc + quad * 8);
        bf16x8 aq2 = ld8(fqp + (base + arow) * Hc + hc + quad * 8);
        for (int nt = wv; nt <= t; nt += 4) {
            int key = nt * 16 + ln; if (key > Sc - 1) key = Sc - 1;
            f32x4 acc = (f32x4){0.f, 0.f, 0.f, 0.f};
            acc = __builtin_amdgcn_mfma_f32_16x16x32_bf16(aq0, ld8(kp + (base + key) * Hc + hc + quad * 8), acc, 0, 0, 0);
            acc = __builtin_amdgcn_mfma_f32_16x16x32_bf16(aq1, ld8(pkp + (long)key * Hc + hc + quad * 8), acc, 0, 0, 0);
            acc = __builtin_amdgcn_mfma_f32_16x16x32_bf16(aq2, ld8(fkp + (base + key) * Hc + hc + quad * 8), acc, 0, 0, 0);
#pragma unroll
            for (int reg = 0; reg < 4; reg++)
                Sm[(quad * 4 + reg) * 208 + nt * 16 + ln] = acc[reg] * scale;
        }
        __syncthreads();
        for (int ri = 0; ri < 4; ri++) {
            int r = wv * 4 + ri;
            int qrow = t * 16 + r;
            float sv[4]; float mx = -1e30f;
#pragma unroll
            for (int j = 0; j < 4; j++) {
                int k = lane + 64 * j;
                sv[j] = (k <= qrow && k < 208) ? Sm[r * 208 + k] : -1e30f;
                mx = fmaxf(mx, sv[j]);
            }
#pragma unroll
            for (int m = 1; m <= 32; m <<= 1) mx = fmaxf(mx, __shfl_xor(mx, m, 64));
            float sum = 0.f; float pv[4];
#pragma unroll
            for (int j = 0; j < 4; j++) {
                float e = (sv[j] > -1e29f) ? __expf(sv[j] - mx) : 0.f;
                pv[j] = e; sum += e;
            }
#pragma unroll
            for (int m = 1; m <= 32; m <<= 1) sum += __shfl_xor(sum, m, 64);
            float inv = 1.f / sum;
#pragma unroll
            for (int j = 0; j < 4; j++) {
                int k = lane + 64 * j;
                if (k < 224) P[r * 416 + k] = f2bf(pv[j] * inv);
            }
        }
        __syncthreads();
        if (wv < 2) {
            int ksteps = (t + 2) >> 1;
            f32x4 acc = (f32x4){0.f, 0.f, 0.f, 0.f};
            const char* Pb = (const char*)Sm;
            for (int ks = 0; ks < ksteps; ks++) {
                bf16x8 pa = *(const bf16x8*)(Pb + ln * 832 + ks * 64 + quad * 16);
                bf16x8 vb = *(const bf16x8*)(&Vt[(wv * 16 + ln) * 224 + ks * 32 + quad * 8]);
                acc = __builtin_amdgcn_mfma_f32_16x16x32_bf16(pa, vb, acc, 0, 0, 0);
            }
#pragma unroll
            for (int reg = 0; reg < 4; reg++) {
                int r = t * 16 + quad * 4 + reg;
                if (r < Sc) ctx[(base + r) * Hc + hc + wv * 16 + ln] = f2bf(acc[reg]);
            }
        }
    }
}

// ---------- fused: t = ctx@Wo+bo+Qn; u = LN(t); q = relu(u@W1+b1)@W2+b2+u; q *= keep ----------
__global__ __launch_bounds__(256) void ffn_kernel(
    const __bf16* __restrict__ ctx, const __bf16* __restrict__ Qn,
    const __bf16* __restrict__ WtO, const __bf16* __restrict__ Wt1, const __bf16* __restrict__ Wt2,
    const float* __restrict__ bo, const float* __restrict__ b1, const float* __restrict__ b2,
    const float* __restrict__ fg, const float* __restrict__ fb,
    const int* __restrict__ tseq, __bf16* __restrict__ qout)
{
    __shared__ __bf16 T1[4][16 * 64];
    __shared__ __bf16 T2[4][16 * 64];
    int lane = threadIdx.x & 63, wv = threadIdx.x >> 6;
    int ln = lane & 15, quad = lane >> 4;
    int m0 = blockIdx.x * 64 + wv * 16;

    bf16x8 ac0 = ld8(ctx + (long)(m0 + ln) * 64 + quad * 8);
    bf16x8 ac1 = ld8(ctx + (long)(m0 + ln) * 64 + 32 + quad * 8);

    float tv[16];
#pragma unroll
    for (int nt = 0; nt < 4; nt++) {
        int col = nt * 16 + ln;
        bf16x8 w0 = ld8(WtO + col * 64 + quad * 8);
        bf16x8 w1 = ld8(WtO + col * 64 + 32 + quad * 8);
        f32x4 acc = (f32x4){0.f, 0.f, 0.f, 0.f};
        acc = __builtin_amdgcn_mfma_f32_16x16x32_bf16(ac0, w0, acc, 0, 0, 0);
        acc = __builtin_amdgcn_mfma_f32_16x16x32_bf16(ac1, w1, acc, 0, 0, 0);
        float bov = bo[col];
#pragma unroll
        for (int reg = 0; reg < 4; reg++)
            tv[nt * 4 + reg] = acc[reg] + bov + bf2f(Qn[(long)(m0 + quad * 4 + reg) * 64 + col]);
    }
    // LN in D-layout: row quad*4+reg lives on the 16 lanes sharing this quad
    float s[4] = {0, 0, 0, 0}, s2[4] = {0, 0, 0, 0};
#pragma unroll
    for (int reg = 0; reg < 4; reg++)
#pragma unroll
        for (int nt = 0; nt < 4; nt++) { float v = tv[nt * 4 + reg]; s[reg] += v; s2[reg] += v * v; }
#pragma unroll
    for (int m = 1; m <= 8; m <<= 1)
#pragma unroll
        for (int reg = 0; reg < 4; reg++) { s[reg] += __shfl_xor(s[reg], m, 64); s2[reg] += __shfl_xor(s2[reg], m, 64); }
    float uv[16];
#pragma unroll
    for (int reg = 0; reg < 4; reg++) {
        float mean = s[reg] * (1.f / 64.f);
        float inv = rsqrtf(s2[reg] * (1.f / 64.f) - mean * mean + 1e-8f);
#pragma unroll
        for (int nt = 0; nt < 4; nt++) {
            int col = nt * 16 + ln;
            float u = (tv[nt * 4 + reg] - mean) * inv * fg[col] + fb[col];
            uv[nt * 4 + reg] = u;
            T1[wv][(quad * 4 + reg) * 64 + col] = f2bf(u);
        }
    }
    __syncthreads();
    bf16x8 au0 = ld8(&T1[wv][ln * 64 + quad * 8]);
    bf16x8 au1 = ld8(&T1[wv][ln * 64 + 32 + quad * 8]);
#pragma unroll
    for (int nt = 0; nt < 4; nt++) {
        int col = nt * 16 + ln;
        bf16x8 w0 = ld8(Wt1 + col * 64 + quad * 8);
        bf16x8 w1 = ld8(Wt1 + col * 64 + 32 + quad * 8);
        f32x4 acc = (f32x4){0.f, 0.f, 0.f, 0.f};
        acc = __builtin_amdgcn_mfma_f32_16x16x32_bf16(au0, w0, acc, 0, 0, 0);
        acc = __builtin_amdgcn_mfma_f32_16x16x32_bf16(au1, w1, acc, 0, 0, 0);
        float b1v = b1[col];
#pragma unroll
        for (int reg = 0; reg < 4; reg++)
            T2[wv][(quad * 4 + reg) * 64 + col] = f2bf(fmaxf(acc[reg] + b1v, 0.f));
    }
    __syncthreads();
    bf16x8 ah0 = ld8(&T2[wv][ln * 64 + quad * 8]);
    bf16x8 ah1 = ld8(&T2[wv][ln * 64 + 32 + quad * 8]);
#pragma unroll
    for (int nt = 0; nt < 4; nt++) {
        int col = nt * 16 + ln;
        bf16x8 w0 = ld8(Wt2 + col * 64 + quad * 8);
        bf16x8 w1 = ld8(Wt2 + col * 64 + 32 + quad * 8);
        f32x4 acc = (f32x4){0.f, 0.f, 0.f, 0.f};
        acc = __builtin_amdgcn_mfma_f32_16x16x32_bf16(ah0, w0, acc, 0, 0, 0);
        acc = __builtin_amdgcn_mfma_f32_16x16x32_bf16(ah1, w1, acc, 0, 0, 0);
        float b2v = b2[col];
#pragma unroll
        for (int reg = 0; reg < 4; reg++) {
            int r = m0 + quad * 4 + reg;
            float v = acc[reg] + b2v + uv[nt * 4 + reg];
            v *= (tseq[r] != 0) ? 1.f : 0.f;
            qout[(long)r * 64 + col] = f2bf(v);
        }
    }
}

// ---------- final LN + logits ----------
__global__ __launch_bounds__(256) void logits_kernel(
    const __bf16* __restrict__ q, const int* __restrict__ pos, const int* __restrict__ neg,
    const float* __restrict__ item, const float* __restrict__ lg, const float* __restrict__ lb,
    float* __restrict__ out)
{
    int row = blockIdx.x * 4 + (threadIdx.x >> 6);
    int lane = threadIdx.x & 63;
    float v = bf2f(q[(long)row * Hc + lane]);
    float s = v, s2 = v * v;
#pragma unroll
    for (int m = 1; m <= 32; m <<= 1) { s += __shfl_xor(s, m, 64); s2 += __shfl_xor(s2, m, 64); }
    float mean = s * (1.f / 64.f);
    float inv = rsqrtf(s2 * (1.f / 64.f) - mean * mean + 1e-8f);
    float lf = (v - mean) * inv * lg[lane] + lb[lane];
    long p = pos[row], n = neg[row];
    float dp = lf * item[p * Hc + lane];
    float dn = lf * item[n * Hc + lane];
#pragma unroll
    for (int m = 1; m <= 32; m <<= 1) { dp += __shfl_xor(dp, m, 64); dn += __shfl_xor(dn, m, 64); }
    if (lane == 0) { out[row] = dp; out[NROWS + row] = dn; }
}

// ---------- launch ----------
extern "C" void kernel_launch(void* const* d_in, const int* in_sizes, int n_in,
                              void* d_out, int out_size, void* d_ws, size_t ws_size,
                              hipStream_t stream)
{
    const int* tseq = (const int*)d_in[0];
    const int* pos  = (const int*)d_in[1];
    const int* neg  = (const int*)d_in[2];
    const float* rev   = (const float*)d_in[3];
    const float* meta  = (const float*)d_in[4];
    const float* item  = (const float*)d_in[5];
    const float* pe    = (const float*)d_in[6];
    const float* featW = (const float*)d_in[7];
    const float* featb = (const float*)d_in[8];
    const float* rg    = (const float*)d_in[9];
    const float* rb    = (const float*)d_in[10];
    const float* Wq = (const float*)d_in[11]; const float* Wk = (const float*)d_in[12];
    const float* Wv = (const float*)d_in[13]; const float* Wpq = (const float*)d_in[14];
    const float* Wpk = (const float*)d_in[15]; const float* Wfq = (const float*)d_in[16];
    const float* Wfk = (const float*)d_in[17]; const float* Wo = (const float*)d_in[18];
    const float* W1 = (const float*)d_in[19]; const float* W2 = (const float*)d_in[20];
    const float* bq = (const float*)d_in[21]; const float* bk = (const float*)d_in[22];
    const float* bv = (const float*)d_in[23]; const float* bpq = (const float*)d_in[24];
    const float* bpk = (const float*)d_in[25]; const float* bfq = (const float*)d_in[26];
    const float* bfk = (const float*)d_in[27]; const float* bo = (const float*)d_in[28];
    const float* b1 = (const float*)d_in[29]; const float* b2 = (const float*)d_in[30];
    const float* ag = (const float*)d_in[31]; const float* ab = (const float*)d_in[32];
    const float* fg = (const float*)d_in[33]; const float* fb = (const float*)d_in[34];
    const float* lg = (const float*)d_in[35]; const float* lb = (const float*)d_in[36];
    float* out = (float*)d_out;

    __bf16* wsb = (__bf16*)d_ws;
    const size_t F = (size_t)NROWS * Hc;
    __bf16* feat = wsb;
    __bf16* q    = wsb + 1 * F;
    __bf16* Qn   = wsb + 2 * F;
    __bf16* qp   = wsb + 3 * F;   // also ctx (phase-disjoint rows)
    __bf16* kp   = wsb + 4 * F;
    __bf16* vp   = wsb + 5 * F;
    __bf16* fqp  = wsb + 6 * F;
    __bf16* fkp  = wsb + 7 * F;
    __bf16* pqp  = wsb + 8 * F;                    // [2][200][64]
    __bf16* pkp  = pqp + 2 * Sc * Hc;
    __bf16* featWt = pkp + 2 * Sc * Hc;            // [64][768]
    __bf16* Wt     = featWt + Ec * Hc;             // [10][2][64][64]

    const int PB = NROWS / 64;     // 800
    const int LB = NROWS / 4;      // 12800

    wconv_kernel<<<512, 256, 0, stream>>>(featW, Wq, Wk, Wv, Wpq, Wpk, Wfq, Wfk, Wo, W1, W2,
                                          featWt, Wt);
    qinit_kernel<<<NROWS * Hc / 8 / 256, 256, 0, stream>>>(tseq, item, q);
    feat_kernel<<<PB, 256, 0, stream>>>(tseq, rev, meta, featWt, featb, rg, rb, feat);
    pe_kernel<<<8, 256, 0, stream>>>(pe, Wt, bpq, bpk, pqp, pkp);

    for (int i = 0; i < 2; i++) {
        qkvf_kernel<<<PB, 256, 0, stream>>>(q, feat, Wt, i,
                                            bq, bk, bv, bfq, bfk, ag, ab,
                                            Qn, qp, kp, vp, fqp, fkp);
        attn_kernel<<<Bc * 2, 256, 0, stream>>>(qp, kp, vp,
                                                pqp + i * Sc * Hc, pkp + i * Sc * Hc,
                                                fqp, fkp, /*ctx=*/qp);
        ffn_kernel<<<PB, 256, 0, stream>>>(qp, Qn,
                                           Wt + 7 * 8192 + i * 4096,
                                           Wt + 8 * 8192 + i * 4096,
                                           Wt + 9 * 8192 + i * 4096,
                                           bo + i * 64, b1 + i * 64, b2 + i * 64,
                                           fg + i * 64, fb + i * 64, tseq, q);
    }
    logits_kernel<<<LB, 256, 0, stream>>>(q, pos, neg, item, lg, lb, out);
}